// Round 1
// baseline (302.945 us; speedup 1.0000x reference)
//
#include <hip/hip_runtime.h>
#include <hip/hip_bf16.h>
#include <cstdint>

#define BS  8
#define NR  2000
#define NC  2000
#define EMB 128

#define TR 32        // rows per block
#define CC 32        // c-chunk
#define NCHUNK 63    // ceil(2000/32)
#define NTILE 63     // ceil(2000/32) row tiles per batch

typedef float f32x4 __attribute__((ext_vector_type(4)));

// ---------------- Kernel 1: projections ----------------
// rp[b*NR+r] = dot(row_emb, w_row); sa[b*NR+r] = leaky(dot(row_emb, w_row+w_col));
// cp[b*NC+c] = dot(col_emb, w_col)
__global__ __launch_bounds__(256) void proj_kernel(
    const float* __restrict__ row_emb, const float* __restrict__ col_emb,
    const float* __restrict__ W,
    float* __restrict__ rp, float* __restrict__ cp, float* __restrict__ sa)
{
    int tid  = threadIdx.x;
    int lane = tid & 31;
    int sub  = tid >> 5;
    long long idx = (long long)blockIdx.x * 8 + sub;   // 0..31999

    f32x4 wr = *(const f32x4*)(W + lane * 4);
    f32x4 wc = *(const f32x4*)(W + 128 + lane * 4);

    bool is_row = idx < (long long)BS * NR;
    const float* base = is_row ? (row_emb + idx * EMB)
                               : (col_emb + (idx - (long long)BS * NR) * EMB);
    f32x4 v = *(const f32x4*)(base + lane * 4);

    float d1, d2;
    if (is_row) {
        d1 = v.x * wr.x + v.y * wr.y + v.z * wr.z + v.w * wr.w;
        d2 = v.x * wc.x + v.y * wc.y + v.z * wc.z + v.w * wc.w;
    } else {
        d1 = v.x * wc.x + v.y * wc.y + v.z * wc.z + v.w * wc.w;
        d2 = 0.f;
    }
    #pragma unroll
    for (int m = 1; m < 32; m <<= 1) {
        d1 += __shfl_xor(d1, m);
        d2 += __shfl_xor(d2, m);
    }
    if (lane == 0) {
        if (is_row) {
            rp[idx] = d1;
            float s = d1 + d2;
            sa[idx] = fmaxf(s, 0.01f * s);
        } else {
            cp[idx - (long long)BS * NR] = d1;
        }
    }
}

// ---------------- Kernel 1b: per-batch max of cp ----------------
__global__ __launch_bounds__(256) void maxcp_kernel(const float* __restrict__ cp,
                                                    float* __restrict__ maxcp)
{
    int b = blockIdx.x, tid = threadIdx.x;
    float m = -1e30f;
    for (int c = tid; c < NC; c += 256) m = fmaxf(m, cp[(size_t)b * NC + c]);
    #pragma unroll
    for (int s = 1; s < 64; s <<= 1) m = fmaxf(m, __shfl_xor(m, s));
    __shared__ float sm[4];
    if ((tid & 63) == 0) sm[tid >> 6] = m;
    __syncthreads();
    if (tid == 0)
        maxcp[b] = fmaxf(fmaxf(sm[0], sm[1]), fmaxf(sm[2], sm[3]));
}

// async global->LDS, 16B per lane, linear dest
__device__ __forceinline__ void gload16(const float* g, float* l) {
    __builtin_amdgcn_global_load_lds(
        (const __attribute__((address_space(1))) unsigned int*)(const void*)g,
        (__attribute__((address_space(3))) unsigned int*)(void*)l, 16, 0, 0);
}

__device__ __forceinline__ void issue_col_chunk(const float* colb, float* dstbase,
                                                int chunk, int tid) {
    #pragma unroll
    for (int j = 0; j < 4; ++j) {
        int flat = j * 256 + tid;          // float4 index within chunk (0..1023)
        int cc   = flat >> 5;              // 0..31
        int ew   = (flat & 31) << 2;       // 0..124
        int cgl  = chunk * CC + cc;
        if (cgl > NC - 1) cgl = NC - 1;
        const float* g = colb + (size_t)cgl * EMB + ew;
        float* l = dstbase + (size_t)(j * 256 + (tid & ~63)) * 4;  // wave-uniform
        gload16(g, l);
    }
}

// ---------------- Kernel 2: fused softmax + P@col ----------------
__global__ __launch_bounds__(256) void main_kernel(
    const float* __restrict__ row_emb, const float* __restrict__ col_emb,
    const float* __restrict__ cost, const float* __restrict__ rp,
    const float* __restrict__ cp, const float* __restrict__ sa,
    const float* __restrict__ maxcp, float* __restrict__ out)
{
    __shared__ float col_lds[2][CC][EMB];   // 32 KB, double-buffered
    __shared__ float p_lds[CC][TR + 4];     // pad 36: 16B-aligned float4 rows
    __shared__ float cp_sm[2048];           // whole cp row of this batch (+pad)
    __shared__ float l_sm[TR], ps_sm[TR], M_sm[TR], rp_sm[TR];

    const int tid = threadIdx.x;
    const int bid = blockIdx.x;
    const int b   = bid / NTILE;
    const int t   = bid % NTILE;
    const int r0  = t * TR;

    const float* cost_b = cost    + (size_t)b * NR * NC;
    const float* colb   = col_emb + (size_t)b * NC * EMB;

    // phase-1 mapping: one row per thread-octet
    const int p_r   = tid >> 3;          // 0..31
    const int p_ci  = tid & 7;           // 0..7
    const int rglob = r0 + p_r;
    const int rclmp = (rglob < NR) ? rglob : (NR - 1);
    const float* cost_row = cost_b + (size_t)rclmp * NC;

    // phase-2 mapping: 4 rows x 4 emb per thread
    const int eg4 = (tid & 31) << 2;     // emb offset
    const int rg2 = tid >> 5;            // row group 0..7

    // ---- prologue ----
    issue_col_chunk(colb, &col_lds[0][0][0], 0, tid);      // col chunk 0 (first!)
    asm volatile("" ::: "memory");
    f32x4 cost_cur = *(const f32x4*)(cost_row + p_ci * 4); // cost chunk 0
    asm volatile("" ::: "memory");

    // stage cp row into LDS
    for (int i = tid; i < 512; i += 256) {
        int src = i * 4; if (src > NC - 4) src = NC - 4;
        *(f32x4*)&cp_sm[i * 4] = *(const f32x4*)&cp[(size_t)b * NC + src];
    }
    // per-row M / p_self
    if (tid < TR) {
        int rg = r0 + tid; int rc = (rg < NR) ? rg : (NR - 1);
        float rpv = rp[(size_t)b * NR + rc];
        float sav = sa[(size_t)b * NR + rc];
        float M   = fmaxf(fmaxf(0.f, rpv + maxcp[b]), sav);
        M_sm[tid] = M; rp_sm[tid] = rpv; ps_sm[tid] = __expf(sav - M);
    }
    __syncthreads();   // full drain: col0 in LDS, cp_sm/M_sm ready

    const float rp_r = rp_sm[p_r];
    const float M_r  = M_sm[p_r];

    f32x4 a0 = {0,0,0,0}, a1 = {0,0,0,0}, a2 = {0,0,0,0}, a3 = {0,0,0,0};
    float l_part = 0.f;

    for (int k = 0; k < NCHUNK; ++k) {
        const int kn = (k + 1 < NCHUNK) ? (k + 1) : (NCHUNK - 1);
        // prefetch next col chunk (async LDS) then next cost chunk (regs) — order pinned
        issue_col_chunk(colb, &col_lds[(k + 1) & 1][0][0], kn, tid);
        asm volatile("" ::: "memory");
        int cn0 = kn * CC + p_ci * 4;
        if (cn0 > NC - 4) cn0 = NC - 4;
        f32x4 cost_next = *(const f32x4*)(cost_row + cn0);
        asm volatile("" ::: "memory");

        // ---- phase 1: P tile for chunk k ----
        {
            const int c0 = k * CC;
            f32x4 cpv = *(const f32x4*)&cp_sm[c0 + p_ci * 4];
            float lp = 0.f;
            #pragma unroll
            for (int j = 0; j < 4; ++j) {
                int cidx = c0 + p_ci * 4 + j;
                float logit = (rp_r + cpv[j]) * cost_cur[j];
                float act   = fmaxf(logit, 0.01f * logit);
                float pv    = __expf(act - M_r);
                pv = (cidx < NC) ? pv : 0.f;
                p_lds[p_ci * 4 + j][p_r] = pv;
                lp += pv;
            }
            l_part += lp;
        }

        // col(k) already drained by cost_cur's wait (FIFO); keep k+1's 5 ops in flight
        asm volatile("s_waitcnt vmcnt(5) lgkmcnt(0)" ::: "memory");
        __builtin_amdgcn_s_barrier();

        // ---- phase 2: acc += P^T-slice * col chunk ----
        {
            const float* colp = &col_lds[k & 1][0][0];
            #pragma unroll 8
            for (int c = 0; c < CC; ++c) {
                f32x4 p4 = *(const f32x4*)&p_lds[c][rg2 * 4];
                f32x4 cv = *(const f32x4*)(colp + c * EMB + eg4);
                a0 += cv * p4.x;
                a1 += cv * p4.y;
                a2 += cv * p4.z;
                a3 += cv * p4.w;
            }
        }

        asm volatile("s_waitcnt lgkmcnt(0)" ::: "memory");
        __builtin_amdgcn_s_barrier();
        cost_cur = cost_next;
    }

    // ---- epilogue ----
    l_part += __shfl_xor(l_part, 1);
    l_part += __shfl_xor(l_part, 2);
    l_part += __shfl_xor(l_part, 4);
    if (p_ci == 0) l_sm[p_r] = l_part;
    __syncthreads();

    const float* rowb = row_emb + (size_t)b * NR * EMB;
    #pragma unroll
    for (int i = 0; i < 4; ++i) {
        int r   = rg2 * 4 + i;
        int rgl = r0 + r;
        if (rgl < NR) {
            float ps    = ps_sm[r];
            float denom = ps + l_sm[r];
            float inv   = 1.0f / denom;
            f32x4 rv = *(const f32x4*)(rowb + (size_t)rgl * EMB + eg4);
            f32x4 acc = (i == 0) ? a0 : (i == 1) ? a1 : (i == 2) ? a2 : a3;
            f32x4 o = (acc + rv * ps) * inv;
            *(f32x4*)(out + ((size_t)b * NR + rgl) * EMB + eg4) = o;
        }
    }
}

extern "C" void kernel_launch(void* const* d_in, const int* in_sizes, int n_in,
                              void* d_out, int out_size, void* d_ws, size_t ws_size,
                              hipStream_t stream) {
    const float* row_emb = (const float*)d_in[0];
    const float* col_emb = (const float*)d_in[1];
    const float* cost    = (const float*)d_in[2];
    const float* W       = (const float*)d_in[3];
    float* out = (float*)d_out;
    float* ws  = (float*)d_ws;

    float* rp = ws;            // 16000 f32
    float* sa = ws + 16000;    // 16000
    float* cp = ws + 32000;    // 16000
    float* mc = ws + 48000;    // 8

    proj_kernel<<<4000, 256, 0, stream>>>(row_emb, col_emb, W, rp, cp, sa);
    maxcp_kernel<<<BS, 256, 0, stream>>>(cp, mc);
    main_kernel<<<BS * NTILE, 256, 0, stream>>>(row_emb, col_emb, cost, rp, cp, sa, mc, out);
}